// Round 3
// baseline (416.646 us; speedup 1.0000x reference)
//
#include <hip/hip_runtime.h>

// Raw vector type so __builtin_nontemporal_load is legal (HIP float4 is a
// struct; the builtin needs a scalar/vector pointee).
typedef float vf4 __attribute__((ext_vector_type(4)));

constexpr int WAVES_PER_BLOCK = 4;
constexpr int BS_PER_WAVE = 8;

// ---------------------------------------------------------------------------
// Polar projection of 3x3 M onto SO(3) via Wahba/Horn quaternion method:
// R* = argmax_{R in SO(3)} tr(R^T M) = top eigenvector of 4x4 symmetric N(M),
// taken as a quaternion. Cyclic Jacobi, 5 sweeps, all static indexing.
// Equals the reference's U diag(1,1,det(UV^T)) V^T (descending singular vals).
// ---------------------------------------------------------------------------
#define JROT(P, Q)                                                         \
  do {                                                                     \
    float apq = A[P][Q];                                                   \
    if (fabsf(apq) > 1e-20f) {                                             \
      float app = A[P][P], aqq = A[Q][Q];                                  \
      float tau = (aqq - app) / (2.0f * apq);                              \
      float tt = copysignf(1.0f, tau) /                                    \
                 (fabsf(tau) + sqrtf(tau * tau + 1.0f));                   \
      float c = rsqrtf(tt * tt + 1.0f);                                    \
      float s = tt * c;                                                    \
      _Pragma("unroll") for (int k = 0; k < 4; ++k) {                      \
        float t1 = A[k][P], t2 = A[k][Q];                                  \
        A[k][P] = c * t1 - s * t2;                                         \
        A[k][Q] = s * t1 + c * t2;                                         \
      }                                                                    \
      _Pragma("unroll") for (int k = 0; k < 4; ++k) {                      \
        float t1 = A[P][k], t2 = A[Q][k];                                  \
        A[P][k] = c * t1 - s * t2;                                         \
        A[Q][k] = s * t1 + c * t2;                                         \
      }                                                                    \
      _Pragma("unroll") for (int k = 0; k < 4; ++k) {                      \
        float t1 = V[k][P], t2 = V[k][Q];                                  \
        V[k][P] = c * t1 - s * t2;                                         \
        V[k][Q] = s * t1 + c * t2;                                         \
      }                                                                    \
    }                                                                      \
  } while (0)

__device__ __forceinline__ void polar_so3(const float m[9], float* __restrict__ p)
{
    float A[4][4];
    A[0][0] = m[0] + m[4] + m[8];
    A[1][1] = m[0] - m[4] - m[8];
    A[2][2] = m[4] - m[0] - m[8];
    A[3][3] = m[8] - m[0] - m[4];
    A[0][1] = A[1][0] = m[7] - m[5];
    A[0][2] = A[2][0] = m[2] - m[6];
    A[0][3] = A[3][0] = m[3] - m[1];
    A[1][2] = A[2][1] = m[1] + m[3];
    A[1][3] = A[3][1] = m[2] + m[6];
    A[2][3] = A[3][2] = m[5] + m[7];

    float V[4][4] = {{1.f, 0.f, 0.f, 0.f},
                     {0.f, 1.f, 0.f, 0.f},
                     {0.f, 0.f, 1.f, 0.f},
                     {0.f, 0.f, 0.f, 1.f}};

    #pragma unroll
    for (int sweep = 0; sweep < 5; ++sweep) {
        JROT(0, 1); JROT(0, 2); JROT(0, 3);
        JROT(1, 2); JROT(1, 3); JROT(2, 3);
    }

    int best = 0;
    float bd = A[0][0];
    if (A[1][1] > bd) { bd = A[1][1]; best = 1; }
    if (A[2][2] > bd) { bd = A[2][2]; best = 2; }
    if (A[3][3] > bd) { bd = A[3][3]; best = 3; }
    float qw = (best == 0) ? V[0][0] : (best == 1) ? V[0][1] : (best == 2) ? V[0][2] : V[0][3];
    float qx = (best == 0) ? V[1][0] : (best == 1) ? V[1][1] : (best == 2) ? V[1][2] : V[1][3];
    float qy = (best == 0) ? V[2][0] : (best == 1) ? V[2][1] : (best == 2) ? V[2][2] : V[2][3];
    float qz = (best == 0) ? V[3][0] : (best == 1) ? V[3][1] : (best == 2) ? V[3][2] : V[3][3];

    const float nrm = rsqrtf(qw * qw + qx * qx + qy * qy + qz * qz);
    qw *= nrm; qx *= nrm; qy *= nrm; qz *= nrm;

    const float xx = qx * qx, yy = qy * qy, zz = qz * qz;
    const float xy = qx * qy, xz = qx * qz, yz = qy * qz;
    const float wx = qw * qx, wy = qw * qy, wz = qw * qz;

    p[0] = 1.0f - 2.0f * (yy + zz);
    p[1] = 2.0f * (xy - wz);
    p[2] = 2.0f * (xz + wy);
    p[3] = 2.0f * (xy + wz);
    p[4] = 1.0f - 2.0f * (xx + zz);
    p[5] = 2.0f * (yz - wx);
    p[6] = 2.0f * (xz - wy);
    p[7] = 2.0f * (yz + wx);
    p[8] = 1.0f - 2.0f * (xx + yy);
}

// ---------------------------------------------------------------------------
// Fused kernel. One wave handles 8 consecutive batch elements:
//   per b: coalesced nontemporal load (9 x dwordx4, 16 lines each) ->
//   LDS transpose (conflict-free: write slots l+64k, read slots 9l+k;
//   both uniform 8-lanes-per-4-bank-group, 9 == 1 mod 8) ->
//   36 static FMAs -> 64-lane xor butterfly (all lanes get full camera) ->
//   lane i stashes camera of b0+i.
// Epilogue: lanes 0..7 run the Jacobi polar projection (one b each) and
// store the 3x3 result. No intermediate HBM round-trip, one launch total.
// ---------------------------------------------------------------------------
__global__ __launch_bounds__(256, 4) void camera_orth_kernel(
    const vf4* __restrict__ x4, const float* __restrict__ W,
    float* __restrict__ out, int B)
{
    __shared__ vf4 tile[WAVES_PER_BLOCK][576];   // 36 KB/block -> 4 blocks/CU
    const int wave = threadIdx.x >> 6;
    const int lane = threadIdx.x & 63;
    const int b0 = (blockIdx.x * WAVES_PER_BLOCK + wave) * BS_PER_WAVE;
    const vf4 wv = reinterpret_cast<const vf4*>(W)[lane];
    vf4* my = tile[wave];

    float cam[9];

    for (int i = 0; i < BS_PER_WAVE; ++i) {
        const int b = b0 + i;
        if (b >= B) break;  // wave-uniform

        // coalesced, streamed-once -> nontemporal (keep L2/LLC clean)
        const vf4* src = x4 + (size_t)b * 576 + lane;
        vf4 r[9];
        #pragma unroll
        for (int k = 0; k < 9; ++k)
            r[k] = __builtin_nontemporal_load(src + (size_t)k * 64);

        // LDS transpose (same-wave write->read; compiler inserts lgkmcnt)
        #pragma unroll
        for (int k = 0; k < 9; ++k) my[lane + 64 * k] = r[k];

        float a0 = 0.f, a1 = 0.f, a2 = 0.f, a3 = 0.f, a4 = 0.f,
              a5 = 0.f, a6 = 0.f, a7 = 0.f, a8 = 0.f;
        vf4 v;
        // lane l holds floats [36l,36l+36) = channels 4l..4l+3; static map
        v = my[9*lane+0]; a0 += v.x*wv.x; a1 += v.y*wv.x; a2 += v.z*wv.x; a3 += v.w*wv.x;
        v = my[9*lane+1]; a4 += v.x*wv.x; a5 += v.y*wv.x; a6 += v.z*wv.x; a7 += v.w*wv.x;
        v = my[9*lane+2]; a8 += v.x*wv.x; a0 += v.y*wv.y; a1 += v.z*wv.y; a2 += v.w*wv.y;
        v = my[9*lane+3]; a3 += v.x*wv.y; a4 += v.y*wv.y; a5 += v.z*wv.y; a6 += v.w*wv.y;
        v = my[9*lane+4]; a7 += v.x*wv.y; a8 += v.y*wv.y; a0 += v.z*wv.z; a1 += v.w*wv.z;
        v = my[9*lane+5]; a2 += v.x*wv.z; a3 += v.y*wv.z; a4 += v.z*wv.z; a5 += v.w*wv.z;
        v = my[9*lane+6]; a6 += v.x*wv.z; a7 += v.y*wv.z; a8 += v.z*wv.z; a0 += v.w*wv.w;
        v = my[9*lane+7]; a1 += v.x*wv.w; a2 += v.y*wv.w; a3 += v.z*wv.w; a4 += v.w*wv.w;
        v = my[9*lane+8]; a5 += v.x*wv.w; a6 += v.y*wv.w; a7 += v.z*wv.w; a8 += v.w*wv.w;

        // 64-lane xor butterfly: every lane ends with the full camera
        #pragma unroll
        for (int m = 32; m >= 1; m >>= 1) {
            a0 += __shfl_xor(a0, m, 64);
            a1 += __shfl_xor(a1, m, 64);
            a2 += __shfl_xor(a2, m, 64);
            a3 += __shfl_xor(a3, m, 64);
            a4 += __shfl_xor(a4, m, 64);
            a5 += __shfl_xor(a5, m, 64);
            a6 += __shfl_xor(a6, m, 64);
            a7 += __shfl_xor(a7, m, 64);
            a8 += __shfl_xor(a8, m, 64);
        }

        // lane i keeps b0+i's camera for the epilogue
        if (lane == i) {
            cam[0] = a0; cam[1] = a1; cam[2] = a2;
            cam[3] = a3; cam[4] = a4; cam[5] = a5;
            cam[6] = a6; cam[7] = a7; cam[8] = a8;
        }
    }

    // Epilogue: 8 active lanes, one SO(3) projection each (~5 us device-wide,
    // overlapped with other waves' HBM stalls).
    const int b = b0 + lane;
    if (lane < BS_PER_WAVE && b < B) {
        polar_so3(cam, out + (size_t)b * 9);
    }
}

extern "C" void kernel_launch(void* const* d_in, const int* in_sizes, int n_in,
                              void* d_out, int out_size, void* d_ws, size_t ws_size,
                              hipStream_t stream)
{
    const float* x = (const float*)d_in[0];
    const float* W = (const float*)d_in[1];
    float* out = (float*)d_out;

    const int C = in_sizes[1];           // 256
    const int B = in_sizes[0] / (C * 9); // 32768

    const int waves_needed = (B + BS_PER_WAVE - 1) / BS_PER_WAVE;
    const int blocks = (waves_needed + WAVES_PER_BLOCK - 1) / WAVES_PER_BLOCK;

    camera_orth_kernel<<<blocks, 256, 0, stream>>>(
        (const vf4*)x, W, out, B);
}